// Round 2
// baseline (541.263 us; speedup 1.0000x reference)
//
#include <hip/hip_runtime.h>
#include <math.h>

#define TAU 0.07f
#define INV_TAU (1.0f / TAU)
#define BLOCK 256

// ---------------- prep: per-column coefficient + global label totals ----------------
// cvals[j] = alpha_j if label==1, beta_j if label==-1, else 0
// totals[0..3] = {count_pos, count_rn, count_u, sum_alpha_over_pos}
__global__ __launch_bounds__(BLOCK) void prep_kernel(
    const float* __restrict__ alphas, const float* __restrict__ betas,
    const int* __restrict__ labels, float* __restrict__ cvals,
    float* __restrict__ totals, int n)
{
    int j = blockIdx.x * BLOCK + threadIdx.x;
    float p = 0.f, r = 0.f, u = 0.f, sa = 0.f;
    if (j < n) {
        int lb = labels[j];
        float a = alphas[j], b = betas[j];
        float c = (lb == 1) ? a : ((lb == -1) ? b : 0.0f);
        cvals[j] = c;
        p  = (lb == 1)  ? 1.f : 0.f;
        r  = (lb == -1) ? 1.f : 0.f;
        u  = (lb == 0)  ? 1.f : 0.f;
        sa = (lb == 1)  ? a   : 0.f;
    }
    // wave (64-lane) butterfly reduce
    #pragma unroll
    for (int off = 1; off < 64; off <<= 1) {
        p  += __shfl_xor(p,  off);
        r  += __shfl_xor(r,  off);
        u  += __shfl_xor(u,  off);
        sa += __shfl_xor(sa, off);
    }
    if ((threadIdx.x & 63) == 0) {
        atomicAdd(&totals[0], p);
        atomicAdd(&totals[1], r);
        atomicAdd(&totals[2], u);
        atomicAdd(&totals[3], sa);
    }
}

// ---------------- main: one block per row, online-max single pass ----------------
__global__ __launch_bounds__(BLOCK) void row_kernel(
    const float* __restrict__ sim, const float* __restrict__ w,
    const float* __restrict__ cvals, const int* __restrict__ labels,
    const float* __restrict__ alphas, const float* __restrict__ pi_a,
    const float* __restrict__ totals, float* __restrict__ out, int n)
{
    const int i = blockIdx.x;
    const int t = threadIdx.x;
    const float* __restrict__ srow = sim + (size_t)i * (size_t)n;
    const float* __restrict__ wrow = w   + (size_t)i * (size_t)n;

    float m = -3.0e38f;               // running max of logits (valid only)
    float Sall = 0.f;                 // sum exp(l - m), j != i
    float Srn  = 0.f;                 // sum_{rn}  beta_j * w_ij * exp(l - m)
    float Su   = 0.f;                 // sum_{u}   w_ij * exp(l - m)
    float Sp   = 0.f;                 // sum_{pos} exp(l - m)
    float A    = 0.f;                 // sum_{pos} alpha_j * l_ij   (plain sum)

    const int nv = n >> 2;            // float4 count
    for (int j4 = t; j4 < nv; j4 += BLOCK) {
        float4 s4 = ((const float4*)srow)[j4];
        float4 w4 = ((const float4*)wrow)[j4];
        float4 c4 = ((const float4*)cvals)[j4];
        int4   b4 = ((const int4*)labels)[j4];
        int jbase = j4 << 2;
        float ls[4]  = {s4.x * INV_TAU, s4.y * INV_TAU, s4.z * INV_TAU, s4.w * INV_TAU};
        float wv_[4] = {w4.x, w4.y, w4.z, w4.w};
        float cs[4]  = {c4.x, c4.y, c4.z, c4.w};
        int   lb_[4] = {b4.x, b4.y, b4.z, b4.w};
        #pragma unroll
        for (int q = 0; q < 4; ++q) {
            int   j     = jbase + q;
            bool  valid = (j != i);
            float l     = ls[q];
            float lv    = valid ? l : -3.0e38f;
            if (lv > m) {             // rare: rescale running sums to new max
                float sc = __expf(m - lv);
                Sall *= sc; Srn *= sc; Su *= sc; Sp *= sc;
                m = lv;
            }
            float e = valid ? __expf(l - m) : 0.0f;
            Sall += e;
            float te = wv_[q] * e;
            int lb = lb_[q];
            Srn += (lb == -1) ? cs[q] * te : 0.0f;
            Su  += (lb == 0)  ? te         : 0.0f;
            Sp  += (lb == 1)  ? e          : 0.0f;
            A   += (lb == 1 && valid) ? cs[q] * l : 0.0f;
        }
    }

    // wave-level max-merge butterfly reduce
    #pragma unroll
    for (int off = 1; off < 64; off <<= 1) {
        float m2  = __shfl_xor(m,    off);
        float Sa2 = __shfl_xor(Sall, off);
        float Sr2 = __shfl_xor(Srn,  off);
        float Su2 = __shfl_xor(Su,   off);
        float Sp2 = __shfl_xor(Sp,   off);
        float A2  = __shfl_xor(A,    off);
        float M   = fmaxf(m, m2);
        float sc1 = __expf(m  - M);
        float sc2 = __expf(m2 - M);
        Sall = Sall * sc1 + Sa2 * sc2;
        Srn  = Srn  * sc1 + Sr2 * sc2;
        Su   = Su   * sc1 + Su2 * sc2;
        Sp   = Sp   * sc1 + Sp2 * sc2;
        A   += A2;
        m    = M;
    }

    // cross-wave merge via LDS (4 waves)
    __shared__ float red[4][6];
    int wid = t >> 6, lane = t & 63;
    if (lane == 0) {
        red[wid][0] = m;  red[wid][1] = Sall; red[wid][2] = Srn;
        red[wid][3] = Su; red[wid][4] = Sp;   red[wid][5] = A;
    }
    __syncthreads();
    if (t == 0) {
        float M  = red[0][0], Sa = red[0][1], Sr = red[0][2];
        float SU = red[0][3], SP = red[0][4], AF = red[0][5];
        #pragma unroll
        for (int wv = 1; wv < 4; ++wv) {
            float m2  = red[wv][0];
            float Mn  = fmaxf(M, m2);
            float sc1 = __expf(M  - Mn);
            float sc2 = __expf(m2 - Mn);
            Sa = Sa * sc1 + red[wv][1] * sc2;
            Sr = Sr * sc1 + red[wv][2] * sc2;
            SU = SU * sc1 + red[wv][3] * sc2;
            SP = SP * sc1 + red[wv][4] * sc2;
            AF += red[wv][5];
            M   = Mn;
        }
        float logZ = M + __logf(Sa);

        int   myl  = labels[i];
        float cntP = totals[0] - ((myl == 1)  ? 1.f : 0.f);
        float cntR = totals[1] - ((myl == -1) ? 1.f : 0.f);
        float cntU = totals[2] - ((myl == 0)  ? 1.f : 0.f);
        float SAp  = totals[3] - ((myl == 1)  ? alphas[i] : 0.f);

        bool hasP = cntP > 0.f, hasR = cntR > 0.f, hasU = cntU > 0.f;
        float invSa = 1.0f / Sa;

        // L_pos = -(A - logZ * sum_pos_alpha) / max(cntP,1)
        float Lpos = hasP ? -(AF - logZ * SAp) / fmaxf(cntP, 1.f) : 0.f;
        // L_rn = (Srn / Sall) / max(cntR,1)
        float Lrn  = hasR ? (Sr * invSa) / fmaxf(cntR, 1.f) : 0.f;
        // debiased unlabeled term
        float EU = (SU * invSa) / fmaxf(cntU, 1.f);
        float EP = (SP * invSa) / fmaxf(cntP, 1.f);
        float pi = fminf(fmaxf(pi_a[i], 1e-4f), 0.5f);
        float deb = (EU - pi * EP) / (1.0f - pi + 1e-8f);
        float Lu = fmaxf(deb, 0.0f);
        if (!(hasU && hasP)) Lu = 0.f;

        float loss = Lpos + Lrn + Lu;
        atomicAdd(out, loss * (1.0f / (float)n));
    }
}

extern "C" void kernel_launch(void* const* d_in, const int* in_sizes, int n_in,
                              void* d_out, int out_size, void* d_ws, size_t ws_size,
                              hipStream_t stream) {
    const float* sim    = (const float*)d_in[0];
    const float* alphas = (const float*)d_in[1];
    const float* betas  = (const float*)d_in[2];
    const float* pi_a   = (const float*)d_in[3];
    const float* w      = (const float*)d_in[4];
    const int*   labels = (const int*)d_in[5];
    float* out = (float*)d_out;
    int n = in_sizes[1];

    float* totals = (float*)d_ws;
    float* cvals  = (float*)((char*)d_ws + 256);

    hipMemsetAsync(d_ws, 0, 256, stream);               // totals accumulator
    hipMemsetAsync(d_out, 0, sizeof(float), stream);    // loss accumulator

    int nb = (n + BLOCK - 1) / BLOCK;
    prep_kernel<<<nb, BLOCK, 0, stream>>>(alphas, betas, labels, cvals, totals, n);
    row_kernel<<<n, BLOCK, 0, stream>>>(sim, w, cvals, labels, alphas, pi_a, totals, out, n);
}